// Round 3
// baseline (881.595 us; speedup 1.0000x reference)
//
#include <hip/hip_runtime.h>

#define N_NODES 100000
#define N_EDGES 1600000
#define D 128

// ---------------- graph preprocessing ----------------

__global__ void k_degree(const int* __restrict__ dst, int* __restrict__ deg) {
    int e = blockIdx.x * blockDim.x + threadIdx.x;
    if (e < N_EDGES) atomicAdd(&deg[dst[e]], 1);
}

// per-block exclusive scan of deg -> offs, block sums -> bsum
__global__ void k_scan1(const int* __restrict__ deg, int* __restrict__ offs,
                        int* __restrict__ bsum) {
    __shared__ int s[256];
    int i = blockIdx.x * 256 + threadIdx.x;
    int v = (i < N_NODES) ? deg[i] : 0;
    s[threadIdx.x] = v;
    __syncthreads();
    for (int off = 1; off < 256; off <<= 1) {
        int t = (threadIdx.x >= off) ? s[threadIdx.x - off] : 0;
        __syncthreads();
        s[threadIdx.x] += t;
        __syncthreads();
    }
    if (i < N_NODES) offs[i] = s[threadIdx.x] - v;   // exclusive within block
    if (threadIdx.x == 255) bsum[blockIdx.x] = s[255];
}

// exclusive scan of block sums (nb <= 512), in place
__global__ void k_scan2(int* __restrict__ bsum, int nb) {
    __shared__ int s[512];
    int t = threadIdx.x;
    int v = (t < nb) ? bsum[t] : 0;
    s[t] = v;
    __syncthreads();
    for (int off = 1; off < 512; off <<= 1) {
        int u = (t >= off) ? s[t - off] : 0;
        __syncthreads();
        s[t] += u;
        __syncthreads();
    }
    if (t < nb) bsum[t] = s[t] - v;                  // exclusive
}

__global__ void k_scan3(int* __restrict__ offs, const int* __restrict__ bsum,
                        int* __restrict__ cursor) {
    int i = blockIdx.x * 256 + threadIdx.x;
    if (i < N_NODES) {
        int o = offs[i] + bsum[blockIdx.x];
        offs[i] = o;
        cursor[i] = o;   // fill kernel bumps this to place each edge
    }
}

__global__ void k_fill(const int* __restrict__ src, const int* __restrict__ dst,
                       int* __restrict__ cursor, int* __restrict__ csr) {
    int e = blockIdx.x * blockDim.x + threadIdx.x;
    if (e < N_EDGES) {
        int slot = atomicAdd(&cursor[dst[e]], 1);
        csr[slot] = src[e];
    }
}

// ---------------- mean aggregation: one wave per node ----------------

__global__ __launch_bounds__(256) void k_aggr(
    const float* __restrict__ x, const int* __restrict__ offs,
    const int* __restrict__ deg, const int* __restrict__ csr,
    float* __restrict__ aggr)
{
    int wave = threadIdx.x >> 6;
    int lane = threadIdx.x & 63;
    int node = blockIdx.x * 4 + wave;
    if (node >= N_NODES) return;
    int start = offs[node];
    int d = deg[node];
    float2 acc = make_float2(0.f, 0.f);
    int e = 0;
    for (; e + 4 <= d; e += 4) {   // 4-way unroll to overlap gather latency
        int j0 = csr[start + e + 0];
        int j1 = csr[start + e + 1];
        int j2 = csr[start + e + 2];
        int j3 = csr[start + e + 3];
        float2 v0 = *(const float2*)&x[j0 * D + lane * 2];
        float2 v1 = *(const float2*)&x[j1 * D + lane * 2];
        float2 v2 = *(const float2*)&x[j2 * D + lane * 2];
        float2 v3 = *(const float2*)&x[j3 * D + lane * 2];
        acc.x += (v0.x + v1.x) + (v2.x + v3.x);
        acc.y += (v0.y + v1.y) + (v2.y + v3.y);
    }
    for (; e < d; ++e) {
        int j = csr[start + e];
        float2 v = *(const float2*)&x[j * D + lane * 2];
        acc.x += v.x; acc.y += v.y;
    }
    float inv = 1.f / (float)(d > 0 ? d : 1);
    acc.x *= inv; acc.y *= inv;
    *(float2*)&aggr[node * D + lane * 2] = acc;
}

// ---------------- fused GEMM: out = A@Wl + B@Wr + bias (optional relu) ----------------
// BM=64 rows/block, BN=128 (full width), BK=32. 256 threads.
// thread: cx = tid&31 -> cols [4cx..4cx+3]; ry = tid>>5 -> rows ry+8i, i=0..7.

__global__ __launch_bounds__(256) void k_gemm(
    const float* __restrict__ A,    // aggr   [N,D]
    const float* __restrict__ B,    // x or h [N,D]
    const float* __restrict__ Wl,   // [D,D] row-major (k,n)
    const float* __restrict__ Wr,   // [D,D]
    const float* __restrict__ bias, // [D]
    float* __restrict__ out,        // [N,D] (may alias B; each block only touches its own rows)
    int relu)
{
    __shared__ float As[64][40];     // stride 40 floats = 160 B (16B-aligned rows)
    __shared__ float Ws[32][128];

    int tid = threadIdx.x;
    int cx = tid & 31;
    int ry = tid >> 5;
    int row0 = blockIdx.x * 64;

    float4 acc[8];
#pragma unroll
    for (int i = 0; i < 8; ++i) acc[i] = make_float4(0.f, 0.f, 0.f, 0.f);

    for (int pass = 0; pass < 2; ++pass) {
        const float* Ap = pass ? B : A;
        const float* Wp = pass ? Wr : Wl;
        for (int k0 = 0; k0 < D; k0 += 32) {
            // stage A tile: 64 rows x 32 k
            {
                int s = tid & 7;       // float4 slot in k
                int r = tid >> 3;      // 0..31
#pragma unroll
                for (int rep = 0; rep < 2; ++rep) {
                    int rr = r + 32 * rep;
                    int grow = row0 + rr; if (grow > N_NODES - 1) grow = N_NODES - 1;
                    float4 v = *(const float4*)&Ap[grow * D + k0 + s * 4];
                    *(float4*)&As[rr][s * 4] = v;
                }
            }
            // stage W tile: 32 k x 128 n
            {
                int c = tid & 31;
                int kk = tid >> 5;     // 0..7
#pragma unroll
                for (int rep = 0; rep < 4; ++rep) {
                    int k = kk + 8 * rep;
                    float4 v = *(const float4*)&Wp[(k0 + k) * D + c * 4];
                    *(float4*)&Ws[k][c * 4] = v;
                }
            }
            __syncthreads();
#pragma unroll
            for (int kk = 0; kk < 32; kk += 4) {
                float4 w0 = *(const float4*)&Ws[kk + 0][cx * 4];
                float4 w1 = *(const float4*)&Ws[kk + 1][cx * 4];
                float4 w2 = *(const float4*)&Ws[kk + 2][cx * 4];
                float4 w3 = *(const float4*)&Ws[kk + 3][cx * 4];
#pragma unroll
                for (int i = 0; i < 8; ++i) {
                    float4 a = *(const float4*)&As[ry + 8 * i][kk];
                    acc[i].x += a.x * w0.x + a.y * w1.x + a.z * w2.x + a.w * w3.x;
                    acc[i].y += a.x * w0.y + a.y * w1.y + a.z * w2.y + a.w * w3.y;
                    acc[i].z += a.x * w0.z + a.y * w1.z + a.z * w2.z + a.w * w3.z;
                    acc[i].w += a.x * w0.w + a.y * w1.w + a.z * w2.w + a.w * w3.w;
                }
            }
            __syncthreads();
        }
    }

    float4 bv = *(const float4*)&bias[cx * 4];
#pragma unroll
    for (int i = 0; i < 8; ++i) {
        int row = row0 + ry + 8 * i;
        if (row < N_NODES) {
            float4 v;
            v.x = acc[i].x + bv.x;
            v.y = acc[i].y + bv.y;
            v.z = acc[i].z + bv.z;
            v.w = acc[i].w + bv.w;
            if (relu) {
                v.x = fmaxf(v.x, 0.f); v.y = fmaxf(v.y, 0.f);
                v.z = fmaxf(v.z, 0.f); v.w = fmaxf(v.w, 0.f);
            }
            *(float4*)&out[row * D + cx * 4] = v;
        }
    }
}

// ---------------- launch ----------------

static inline size_t align_up(size_t v, size_t a) { return (v + a - 1) / a * a; }

extern "C" void kernel_launch(void* const* d_in, const int* in_sizes, int n_in,
                              void* d_out, int out_size, void* d_ws, size_t ws_size,
                              hipStream_t stream) {
    const float* x   = (const float*)d_in[0];
    const int*   ei  = (const int*)d_in[1];
    const int*   src = ei;
    const int*   dst = ei + N_EDGES;
    const float* Wl0 = (const float*)d_in[2];
    const float* b0  = (const float*)d_in[3];
    const float* Wr0 = (const float*)d_in[4];
    const float* Wl1 = (const float*)d_in[5];
    const float* b1  = (const float*)d_in[6];
    const float* Wr1 = (const float*)d_in[7];
    float* out = (float*)d_out;   // also holds h between the two layers

    // workspace layout
    char* w = (char*)d_ws;
    int* deg    = (int*)w;                 w += align_up(N_NODES * 4, 256);
    int* offs   = (int*)w;                 w += align_up(N_NODES * 4, 256);
    int* cursor = (int*)w;                 w += align_up(N_NODES * 4, 256);
    int* bsum   = (int*)w;                 w += align_up(512 * 4, 256);
    int* csr    = (int*)w;                 w += align_up((size_t)N_EDGES * 4, 256);
    float* aggr = (float*)w;               w += align_up((size_t)N_NODES * D * 4, 256);

    const int nScanBlocks = (N_NODES + 255) / 256;   // 391
    const int nEdgeBlocks = (N_EDGES + 255) / 256;   // 6250

    hipMemsetAsync(deg, 0, N_NODES * sizeof(int), stream);
    k_degree<<<nEdgeBlocks, 256, 0, stream>>>(dst, deg);
    k_scan1<<<nScanBlocks, 256, 0, stream>>>(deg, offs, bsum);
    k_scan2<<<1, 512, 0, stream>>>(bsum, nScanBlocks);
    k_scan3<<<nScanBlocks, 256, 0, stream>>>(offs, bsum, cursor);
    k_fill<<<nEdgeBlocks, 256, 0, stream>>>(src, dst, cursor, csr);

    const int nAggrBlocks = N_NODES / 4;             // 25000
    const int nGemmBlocks = (N_NODES + 63) / 64;     // 1563

    // layer 0: h = relu(aggr@Wl0 + x@Wr0 + b0) -> out
    k_aggr<<<nAggrBlocks, 256, 0, stream>>>(x, offs, deg, csr, aggr);
    k_gemm<<<nGemmBlocks, 256, 0, stream>>>(aggr, x, Wl0, Wr0, b0, out, 1);

    // layer 1: out = aggr_h@Wl1 + h@Wr1 + b1 (in place over h)
    k_aggr<<<nAggrBlocks, 256, 0, stream>>>(out, offs, deg, csr, aggr);
    k_gemm<<<nGemmBlocks, 256, 0, stream>>>(aggr, out, Wl1, Wr1, b1, out, 0);
}

// Round 5
// 509.451 us; speedup vs baseline: 1.7305x; 1.7305x over previous
//
#include <hip/hip_runtime.h>
#include <hip/hip_bf16.h>

#define N_NODES 100000
#define N_EDGES 1600000
#define D 128

typedef __attribute__((ext_vector_type(8))) short short8;
typedef __attribute__((ext_vector_type(4))) float f32x4;

__device__ __forceinline__ float bf2f(unsigned short u) {
    union { unsigned int i; float f; } c; c.i = ((unsigned int)u) << 16; return c.f;
}
__device__ __forceinline__ unsigned short f2bf(float f) {
    union { float f; unsigned int i; } c; c.f = f;
    unsigned int u = c.i;
    return (unsigned short)((u + 0x7fffu + ((u >> 16) & 1u)) >> 16);   // RNE
}

// ---------------- graph preprocessing (CSR build) ----------------

__global__ void k_degree(const int* __restrict__ dst, int* __restrict__ deg) {
    int e = blockIdx.x * blockDim.x + threadIdx.x;
    if (e < N_EDGES) atomicAdd(&deg[dst[e]], 1);
}

__global__ void k_scan1(const int* __restrict__ deg, int* __restrict__ offs,
                        int* __restrict__ bsum) {
    __shared__ int s[256];
    int i = blockIdx.x * 256 + threadIdx.x;
    int v = (i < N_NODES) ? deg[i] : 0;
    s[threadIdx.x] = v;
    __syncthreads();
    for (int off = 1; off < 256; off <<= 1) {
        int t = (threadIdx.x >= off) ? s[threadIdx.x - off] : 0;
        __syncthreads();
        s[threadIdx.x] += t;
        __syncthreads();
    }
    if (i < N_NODES) offs[i] = s[threadIdx.x] - v;
    if (threadIdx.x == 255) bsum[blockIdx.x] = s[255];
}

__global__ void k_scan2(int* __restrict__ bsum, int nb) {
    __shared__ int s[512];
    int t = threadIdx.x;
    int v = (t < nb) ? bsum[t] : 0;
    s[t] = v;
    __syncthreads();
    for (int off = 1; off < 512; off <<= 1) {
        int u = (t >= off) ? s[t - off] : 0;
        __syncthreads();
        s[t] += u;
        __syncthreads();
    }
    if (t < nb) bsum[t] = s[t] - v;
}

__global__ void k_scan3(int* __restrict__ offs, const int* __restrict__ bsum,
                        int* __restrict__ cursor) {
    int i = blockIdx.x * 256 + threadIdx.x;
    if (i < N_NODES) {
        int o = offs[i] + bsum[blockIdx.x];
        offs[i] = o;
        cursor[i] = o;
    }
}

__global__ void k_fill(const int* __restrict__ src, const int* __restrict__ dst,
                       int* __restrict__ cursor, int* __restrict__ csr) {
    int e = blockIdx.x * blockDim.x + threadIdx.x;
    if (e < N_EDGES) {
        int slot = atomicAdd(&cursor[dst[e]], 1);
        csr[slot] = src[e];
    }
}

// ---------------- casts ----------------

__global__ __launch_bounds__(256) void k_cast_x(const float* __restrict__ x,
                                                unsigned short* __restrict__ xb) {
    int i = blockIdx.x * 256 + threadIdx.x;
    int base = i * 8;
    if (base < N_NODES * D) {
        float4 a = *(const float4*)&x[base];
        float4 b = *(const float4*)&x[base + 4];
        uint4 o;
        o.x = (unsigned)f2bf(a.x) | ((unsigned)f2bf(a.y) << 16);
        o.y = (unsigned)f2bf(a.z) | ((unsigned)f2bf(a.w) << 16);
        o.z = (unsigned)f2bf(b.x) | ((unsigned)f2bf(b.y) << 16);
        o.w = (unsigned)f2bf(b.z) | ((unsigned)f2bf(b.w) << 16);
        *(uint4*)&xb[base] = o;
    }
}

// transpose + cast: W[k][n] fp32 -> Wt[n][k] bf16  (4 tiny matrices, 1 block each)
__global__ void k_cast_w(const float* __restrict__ W0, const float* __restrict__ W1,
                         const float* __restrict__ W2, const float* __restrict__ W3,
                         unsigned short* __restrict__ T) {
    const float* W = (blockIdx.x == 0) ? W0 : (blockIdx.x == 1) ? W1
                     : (blockIdx.x == 2) ? W2 : W3;
    unsigned short* Tm = T + blockIdx.x * D * D;
    int n = threadIdx.x;           // 128 threads
    for (int k = 0; k < D; ++k)
        Tm[n * D + k] = f2bf(W[k * D + n]);
}

// ---------------- mean aggregation (bf16 in/out, fp32 accum) ----------------

__global__ __launch_bounds__(256) void k_aggr_b(
    const unsigned short* __restrict__ xb, const int* __restrict__ offs,
    const int* __restrict__ deg, const int* __restrict__ csr,
    unsigned short* __restrict__ aggrb)
{
    int wave = threadIdx.x >> 6;
    int lane = threadIdx.x & 63;
    int node = blockIdx.x * 4 + wave;
    if (node >= N_NODES) return;
    int start = offs[node];
    int d = deg[node];
    float ax = 0.f, ay = 0.f;
    int e = 0;
    for (; e + 4 <= d; e += 4) {
        int j0 = csr[start + e + 0];
        int j1 = csr[start + e + 1];
        int j2 = csr[start + e + 2];
        int j3 = csr[start + e + 3];
        unsigned v0 = *(const unsigned*)&xb[j0 * D + lane * 2];
        unsigned v1 = *(const unsigned*)&xb[j1 * D + lane * 2];
        unsigned v2 = *(const unsigned*)&xb[j2 * D + lane * 2];
        unsigned v3 = *(const unsigned*)&xb[j3 * D + lane * 2];
        ax += (bf2f(v0 & 0xffff) + bf2f(v1 & 0xffff)) + (bf2f(v2 & 0xffff) + bf2f(v3 & 0xffff));
        ay += (bf2f(v0 >> 16)    + bf2f(v1 >> 16))    + (bf2f(v2 >> 16)    + bf2f(v3 >> 16));
    }
    for (; e < d; ++e) {
        int j = csr[start + e];
        unsigned v = *(const unsigned*)&xb[j * D + lane * 2];
        ax += bf2f(v & 0xffff);
        ay += bf2f(v >> 16);
    }
    float inv = 1.f / (float)(d > 0 ? d : 1);
    unsigned out = (unsigned)f2bf(ax * inv) | ((unsigned)f2bf(ay * inv) << 16);
    *(unsigned*)&aggrb[node * D + lane * 2] = out;
}

// ---------------- MFMA GEMM: out = A@Wl + B@Wr + bias ----------------
// K=256 logical (two bf16 A-sources, two W matrices). BM=64 rows/block,
// 4 waves x 16 rows x full N=128. LDS rows padded to 80B (20 words) so
// fragment ds_read_b128 spreads across 8 bank-groups.

template<int OUT_BF16, int RELU>
__global__ __launch_bounds__(256) void k_gemm_mfma(
    const unsigned short* __restrict__ Ab,   // aggr bf16 [N][D]
    const unsigned short* __restrict__ Bb,   // x/h  bf16 [N][D] (may alias out when OUT_BF16)
    const unsigned short* __restrict__ Wlt,  // [n][k] bf16
    const unsigned short* __restrict__ Wrt,  // [n][k] bf16
    const float* __restrict__ bias,
    void* __restrict__ outp)
{
    __shared__ unsigned short As[64][40];    // 64 rows x 32k (+8 pad)
    __shared__ unsigned short Ws[128][40];   // 128 n  x 32k (+8 pad)

    int tid = threadIdx.x;
    int w = tid >> 6;
    int l = tid & 63;
    int row0 = blockIdx.x * 64;

    f32x4 acc[8];
#pragma unroll
    for (int nt = 0; nt < 8; ++nt) acc[nt] = (f32x4){0.f, 0.f, 0.f, 0.f};

    int r  = tid >> 2;        // 0..63
    int c4 = tid & 3;         // 16B chunk within 64B k-slice
    int arow = row0 + r; if (arow > N_NODES - 1) arow = N_NODES - 1;

    for (int kt = 0; kt < 8; ++kt) {
        const unsigned short* Asrc = (kt < 4) ? Ab : Bb;
        const unsigned short* Wsrc = (kt < 4) ? Wlt : Wrt;
        int k0 = (kt & 3) * 32;
        // stage A tile (64 x 32)
        {
            uint4 v = *(const uint4*)&Asrc[arow * D + k0 + c4 * 8];
            *(uint4*)&As[r][c4 * 8] = v;
        }
        // stage W tile (128 x 32)
#pragma unroll
        for (int rep = 0; rep < 2; ++rep) {
            int n = r + 64 * rep;
            uint4 v = *(const uint4*)&Wsrc[n * D + k0 + c4 * 8];
            *(uint4*)&Ws[n][c4 * 8] = v;
        }
        __syncthreads();
        int kb = l >> 4;
        short8 a = *(const short8*)&As[16 * w + (l & 15)][kb * 8];
#pragma unroll
        for (int nt = 0; nt < 8; ++nt) {
            short8 b = *(const short8*)&Ws[nt * 16 + (l & 15)][kb * 8];
            acc[nt] = __builtin_amdgcn_mfma_f32_16x16x32_bf16(a, b, acc[nt], 0, 0, 0);
        }
        __syncthreads();
    }

    // epilogue: C[row=(l>>4)*4+i][col=l&15] per 16x16 tile (m89-verified layout)
    int rbase = row0 + 16 * w + ((l >> 4) << 2);
    int cbase = l & 15;
#pragma unroll
    for (int nt = 0; nt < 8; ++nt) {
        int col = nt * 16 + cbase;
        float bv = bias[col];
#pragma unroll
        for (int i = 0; i < 4; ++i) {
            int row = rbase + i;
            if (row < N_NODES) {
                float v = acc[nt][i] + bv;
                if (RELU) v = fmaxf(v, 0.f);
                if (OUT_BF16) ((unsigned short*)outp)[row * D + col] = f2bf(v);
                else          ((float*)outp)[row * D + col] = v;
            }
        }
    }
}

// ---------------- launch ----------------

static inline size_t align_up(size_t v, size_t a) { return (v + a - 1) / a * a; }

extern "C" void kernel_launch(void* const* d_in, const int* in_sizes, int n_in,
                              void* d_out, int out_size, void* d_ws, size_t ws_size,
                              hipStream_t stream) {
    const float* x   = (const float*)d_in[0];
    const int*   ei  = (const int*)d_in[1];
    const int*   src = ei;
    const int*   dst = ei + N_EDGES;
    const float* Wl0 = (const float*)d_in[2];
    const float* b0  = (const float*)d_in[3];
    const float* Wr0 = (const float*)d_in[4];
    const float* Wl1 = (const float*)d_in[5];
    const float* b1  = (const float*)d_in[6];
    const float* Wr1 = (const float*)d_in[7];
    float* out = (float*)d_out;

    // workspace layout (~59 MB)
    char* w = (char*)d_ws;
    int* deg    = (int*)w;                  w += align_up(N_NODES * 4, 256);
    int* offs   = (int*)w;                  w += align_up(N_NODES * 4, 256);
    int* cursor = (int*)w;                  w += align_up(N_NODES * 4, 256);
    int* bsum   = (int*)w;                  w += align_up(512 * 4, 256);
    int* csr    = (int*)w;                  w += align_up((size_t)N_EDGES * 4, 256);
    unsigned short* xb    = (unsigned short*)w;  w += align_up((size_t)N_NODES * D * 2, 256); // becomes h after layer 0
    unsigned short* aggrb = (unsigned short*)w;  w += align_up((size_t)N_NODES * D * 2, 256);
    unsigned short* Wt    = (unsigned short*)w;  w += align_up((size_t)4 * D * D * 2, 256);
    unsigned short* Wt_l0 = Wt + 0 * D * D;
    unsigned short* Wt_r0 = Wt + 1 * D * D;
    unsigned short* Wt_l1 = Wt + 2 * D * D;
    unsigned short* Wt_r1 = Wt + 3 * D * D;

    const int nScanBlocks = (N_NODES + 255) / 256;   // 391
    const int nEdgeBlocks = (N_EDGES + 255) / 256;   // 6250
    const int nCastBlocks = (N_NODES * D / 8 + 255) / 256;
    const int nAggrBlocks = N_NODES / 4;             // 25000
    const int nGemmBlocks = (N_NODES + 63) / 64;     // 1563

    hipMemsetAsync(deg, 0, N_NODES * sizeof(int), stream);
    k_degree<<<nEdgeBlocks, 256, 0, stream>>>(dst, deg);
    k_scan1<<<nScanBlocks, 256, 0, stream>>>(deg, offs, bsum);
    k_scan2<<<1, 512, 0, stream>>>(bsum, nScanBlocks);
    k_scan3<<<nScanBlocks, 256, 0, stream>>>(offs, bsum, cursor);
    k_fill<<<nEdgeBlocks, 256, 0, stream>>>(src, dst, cursor, csr);

    k_cast_x<<<nCastBlocks, 256, 0, stream>>>(x, xb);
    k_cast_w<<<4, 128, 0, stream>>>(Wl0, Wr0, Wl1, Wr1, Wt);

    // layer 0: h = relu(aggr@Wl0 + x@Wr0 + b0) -> xb (in place, bf16)
    k_aggr_b<<<nAggrBlocks, 256, 0, stream>>>(xb, offs, deg, csr, aggrb);
    k_gemm_mfma<1, 1><<<nGemmBlocks, 256, 0, stream>>>(aggrb, xb, Wt_l0, Wt_r0, b0, xb);

    // layer 1: out = aggr_h@Wl1 + h@Wr1 + b1 -> d_out (fp32)
    k_aggr_b<<<nAggrBlocks, 256, 0, stream>>>(xb, offs, deg, csr, aggrb);
    k_gemm_mfma<0, 0><<<nGemmBlocks, 256, 0, stream>>>(aggrb, xb, Wt_l1, Wt_r1, b1, out);
}

// Round 6
// 408.985 us; speedup vs baseline: 2.1556x; 1.2456x over previous
//
#include <hip/hip_runtime.h>
#include <hip/hip_bf16.h>

#define N_NODES 100000
#define N_EDGES 1600000
#define D 128

typedef __attribute__((ext_vector_type(8))) short short8;
typedef __attribute__((ext_vector_type(4))) float f32x4;

__device__ __forceinline__ float bf2f(unsigned short u) {
    union { unsigned int i; float f; } c; c.i = ((unsigned int)u) << 16; return c.f;
}
__device__ __forceinline__ unsigned short f2bf(float f) {
    union { float f; unsigned int i; } c; c.f = f;
    unsigned int u = c.i;
    return (unsigned short)((u + 0x7fffu + ((u >> 16) & 1u)) >> 16);   // RNE
}

// ---------------- CSR build, atomic-contention-minimized ----------------
// 8-way privatized degree histogram; atomic return value = per-copy rank,
// so placement needs no atomics at all. copy index = blockIdx&7 (matches
// round-robin XCD dispatch heuristic; correctness doesn't depend on it).

__global__ __launch_bounds__(256) void k_deg8(const int* __restrict__ dst,
                                              int* __restrict__ deg8,
                                              int* __restrict__ rank) {
    int e = blockIdx.x * 256 + threadIdx.x;   // grid sized exactly: 6250*256 == N_EDGES
    int c = blockIdx.x & 7;
    rank[e] = atomicAdd(&deg8[c * N_NODES + dst[e]], 1);
}

__global__ __launch_bounds__(256) void k_sumdeg(const int* __restrict__ deg8,
                                                int* __restrict__ deg) {
    int i = blockIdx.x * 256 + threadIdx.x;
    if (i < N_NODES) {
        int s = 0;
#pragma unroll
        for (int c = 0; c < 8; ++c) s += deg8[c * N_NODES + i];
        deg[i] = s;
    }
}

// per-block exclusive scan of deg -> offsP, block sums -> bsum
__global__ void k_scan1(const int* __restrict__ deg, int* __restrict__ offsP,
                        int* __restrict__ bsum) {
    __shared__ int s[256];
    int i = blockIdx.x * 256 + threadIdx.x;
    int v = (i < N_NODES) ? deg[i] : 0;
    s[threadIdx.x] = v;
    __syncthreads();
    for (int off = 1; off < 256; off <<= 1) {
        int t = (threadIdx.x >= off) ? s[threadIdx.x - off] : 0;
        __syncthreads();
        s[threadIdx.x] += t;
        __syncthreads();
    }
    if (i < N_NODES) offsP[i] = s[threadIdx.x] - v;
    if (threadIdx.x == 255) bsum[blockIdx.x] = s[255];
}

__global__ void k_scan2(int* __restrict__ bsum, int nb) {
    __shared__ int s[512];
    int t = threadIdx.x;
    int v = (t < nb) ? bsum[t] : 0;
    s[t] = v;
    __syncthreads();
    for (int off = 1; off < 512; off <<= 1) {
        int u = (t >= off) ? s[t - off] : 0;
        __syncthreads();
        s[t] += u;
        __syncthreads();
    }
    if (t < nb) bsum[t] = s[t] - v;
}

// offs (global) = offsP + bsum[block];  offs8[c][i] = offs[i] + prefix_c(deg8)
__global__ __launch_bounds__(256) void k_offs8(const int* __restrict__ offsP,
                                               const int* __restrict__ bsum,
                                               const int* __restrict__ deg8,
                                               int* __restrict__ offs,
                                               int* __restrict__ offs8) {
    int i = blockIdx.x * 256 + threadIdx.x;
    if (i < N_NODES) {
        int o = offsP[i] + bsum[blockIdx.x];
        offs[i] = o;
#pragma unroll
        for (int c = 0; c < 8; ++c) {
            offs8[c * N_NODES + i] = o;
            o += deg8[c * N_NODES + i];
        }
    }
}

__global__ __launch_bounds__(256) void k_place(const int* __restrict__ src,
                                               const int* __restrict__ dst,
                                               const int* __restrict__ rank,
                                               const int* __restrict__ offs8,
                                               int* __restrict__ csr) {
    int e = blockIdx.x * 256 + threadIdx.x;   // same geometry as k_deg8
    int c = blockIdx.x & 7;
    int d = dst[e];
    csr[offs8[c * N_NODES + d] + rank[e]] = src[e];
}

// ---------------- casts ----------------

__global__ __launch_bounds__(256) void k_cast_x(const float* __restrict__ x,
                                                unsigned short* __restrict__ xb) {
    int i = blockIdx.x * 256 + threadIdx.x;
    int base = i * 8;
    if (base < N_NODES * D) {
        float4 a = *(const float4*)&x[base];
        float4 b = *(const float4*)&x[base + 4];
        uint4 o;
        o.x = (unsigned)f2bf(a.x) | ((unsigned)f2bf(a.y) << 16);
        o.y = (unsigned)f2bf(a.z) | ((unsigned)f2bf(a.w) << 16);
        o.z = (unsigned)f2bf(b.x) | ((unsigned)f2bf(b.y) << 16);
        o.w = (unsigned)f2bf(b.z) | ((unsigned)f2bf(b.w) << 16);
        *(uint4*)&xb[base] = o;
    }
}

// transpose + cast: W[k][n] fp32 -> Wt[n][k] bf16  (4 tiny matrices, 1 block each)
__global__ void k_cast_w(const float* __restrict__ W0, const float* __restrict__ W1,
                         const float* __restrict__ W2, const float* __restrict__ W3,
                         unsigned short* __restrict__ T) {
    const float* W = (blockIdx.x == 0) ? W0 : (blockIdx.x == 1) ? W1
                     : (blockIdx.x == 2) ? W2 : W3;
    unsigned short* Tm = T + blockIdx.x * D * D;
    int n = threadIdx.x;           // 128 threads
    for (int k = 0; k < D; ++k)
        Tm[n * D + k] = f2bf(W[k * D + n]);
}

// ---------------- mean aggregation (bf16 in/out, fp32 accum) ----------------

__global__ __launch_bounds__(256) void k_aggr_b(
    const unsigned short* __restrict__ xb, const int* __restrict__ offs,
    const int* __restrict__ deg, const int* __restrict__ csr,
    unsigned short* __restrict__ aggrb)
{
    int wave = threadIdx.x >> 6;
    int lane = threadIdx.x & 63;
    int node = blockIdx.x * 4 + wave;
    if (node >= N_NODES) return;
    int start = offs[node];
    int d = deg[node];
    float ax = 0.f, ay = 0.f;
    int e = 0;
    for (; e + 4 <= d; e += 4) {
        int j0 = csr[start + e + 0];
        int j1 = csr[start + e + 1];
        int j2 = csr[start + e + 2];
        int j3 = csr[start + e + 3];
        unsigned v0 = *(const unsigned*)&xb[j0 * D + lane * 2];
        unsigned v1 = *(const unsigned*)&xb[j1 * D + lane * 2];
        unsigned v2 = *(const unsigned*)&xb[j2 * D + lane * 2];
        unsigned v3 = *(const unsigned*)&xb[j3 * D + lane * 2];
        ax += (bf2f(v0 & 0xffff) + bf2f(v1 & 0xffff)) + (bf2f(v2 & 0xffff) + bf2f(v3 & 0xffff));
        ay += (bf2f(v0 >> 16)    + bf2f(v1 >> 16))    + (bf2f(v2 >> 16)    + bf2f(v3 >> 16));
    }
    for (; e < d; ++e) {
        int j = csr[start + e];
        unsigned v = *(const unsigned*)&xb[j * D + lane * 2];
        ax += bf2f(v & 0xffff);
        ay += bf2f(v >> 16);
    }
    float inv = 1.f / (float)(d > 0 ? d : 1);
    unsigned out = (unsigned)f2bf(ax * inv) | ((unsigned)f2bf(ay * inv) << 16);
    *(unsigned*)&aggrb[node * D + lane * 2] = out;
}

// ---------------- MFMA GEMM: out = A@Wl + B@Wr + bias ----------------

template<int OUT_BF16, int RELU>
__global__ __launch_bounds__(256) void k_gemm_mfma(
    const unsigned short* __restrict__ Ab,   // aggr bf16 [N][D]
    const unsigned short* __restrict__ Bb,   // x/h  bf16 [N][D] (may alias out when OUT_BF16)
    const unsigned short* __restrict__ Wlt,  // [n][k] bf16
    const unsigned short* __restrict__ Wrt,  // [n][k] bf16
    const float* __restrict__ bias,
    void* __restrict__ outp)
{
    __shared__ unsigned short As[64][40];    // 64 rows x 32k (+8 pad)
    __shared__ unsigned short Ws[128][40];   // 128 n  x 32k (+8 pad)

    int tid = threadIdx.x;
    int w = tid >> 6;
    int l = tid & 63;
    int row0 = blockIdx.x * 64;

    f32x4 acc[8];
#pragma unroll
    for (int nt = 0; nt < 8; ++nt) acc[nt] = (f32x4){0.f, 0.f, 0.f, 0.f};

    int r  = tid >> 2;        // 0..63
    int c4 = tid & 3;         // 16B chunk within 64B k-slice
    int arow = row0 + r; if (arow > N_NODES - 1) arow = N_NODES - 1;

    for (int kt = 0; kt < 8; ++kt) {
        const unsigned short* Asrc = (kt < 4) ? Ab : Bb;
        const unsigned short* Wsrc = (kt < 4) ? Wlt : Wrt;
        int k0 = (kt & 3) * 32;
        {
            uint4 v = *(const uint4*)&Asrc[arow * D + k0 + c4 * 8];
            *(uint4*)&As[r][c4 * 8] = v;
        }
#pragma unroll
        for (int rep = 0; rep < 2; ++rep) {
            int n = r + 64 * rep;
            uint4 v = *(const uint4*)&Wsrc[n * D + k0 + c4 * 8];
            *(uint4*)&Ws[n][c4 * 8] = v;
        }
        __syncthreads();
        int kb = l >> 4;
        short8 a = *(const short8*)&As[16 * w + (l & 15)][kb * 8];
#pragma unroll
        for (int nt = 0; nt < 8; ++nt) {
            short8 b = *(const short8*)&Ws[nt * 16 + (l & 15)][kb * 8];
            acc[nt] = __builtin_amdgcn_mfma_f32_16x16x32_bf16(a, b, acc[nt], 0, 0, 0);
        }
        __syncthreads();
    }

    // epilogue: C[row=(l>>4)*4+i][col=l&15] per 16x16 tile (m89-verified layout)
    int rbase = row0 + 16 * w + ((l >> 4) << 2);
    int cbase = l & 15;
#pragma unroll
    for (int nt = 0; nt < 8; ++nt) {
        int col = nt * 16 + cbase;
        float bv = bias[col];
#pragma unroll
        for (int i = 0; i < 4; ++i) {
            int row = rbase + i;
            if (row < N_NODES) {
                float v = acc[nt][i] + bv;
                if (RELU) v = fmaxf(v, 0.f);
                if (OUT_BF16) ((unsigned short*)outp)[row * D + col] = f2bf(v);
                else          ((float*)outp)[row * D + col] = v;
            }
        }
    }
}

// ---------------- launch ----------------

static inline size_t align_up(size_t v, size_t a) { return (v + a - 1) / a * a; }

extern "C" void kernel_launch(void* const* d_in, const int* in_sizes, int n_in,
                              void* d_out, int out_size, void* d_ws, size_t ws_size,
                              hipStream_t stream) {
    const float* x   = (const float*)d_in[0];
    const int*   ei  = (const int*)d_in[1];
    const int*   src = ei;
    const int*   dst = ei + N_EDGES;
    const float* Wl0 = (const float*)d_in[2];
    const float* b0  = (const float*)d_in[3];
    const float* Wr0 = (const float*)d_in[4];
    const float* Wl1 = (const float*)d_in[5];
    const float* b1  = (const float*)d_in[6];
    const float* Wr1 = (const float*)d_in[7];
    float* out = (float*)d_out;

    // workspace layout (~58.5 MB); deg8/rank/offs8 overlap aggrb (dead before
    // first k_aggr_b write).
    char* w = (char*)d_ws;
    int* deg    = (int*)w;                  w += align_up(N_NODES * 4, 256);
    int* offs   = (int*)w;                  w += align_up(N_NODES * 4, 256);   // partial, then global
    int* bsum   = (int*)w;                  w += align_up(512 * 4, 256);
    int* csr    = (int*)w;                  w += align_up((size_t)N_EDGES * 4, 256);
    unsigned short* xb    = (unsigned short*)w;  w += align_up((size_t)N_NODES * D * 2, 256); // becomes h after layer 0
    unsigned short* Wt    = (unsigned short*)w;  w += align_up((size_t)4 * D * D * 2, 256);
    unsigned short* aggrb = (unsigned short*)w;  w += align_up((size_t)N_NODES * D * 2, 256);
    // transient region inside aggrb:
    int* deg8  = (int*)aggrb;                          // 8*N ints = 3.2 MB
    int* rank  = deg8 + 8 * N_NODES;                   // 6.4 MB
    int* offs8 = rank + N_EDGES;                       // 3.2 MB   (total 12.8 < 25.6 MB)
    unsigned short* Wt_l0 = Wt + 0 * D * D;
    unsigned short* Wt_r0 = Wt + 1 * D * D;
    unsigned short* Wt_l1 = Wt + 2 * D * D;
    unsigned short* Wt_r1 = Wt + 3 * D * D;

    const int nScanBlocks = (N_NODES + 255) / 256;   // 391
    const int nEdgeBlocks = N_EDGES / 256;           // 6250 (exact)
    const int nCastBlocks = (N_NODES * D / 8 + 255) / 256;
    const int nAggrBlocks = N_NODES / 4;             // 25000
    const int nGemmBlocks = (N_NODES + 63) / 64;     // 1563

    hipMemsetAsync(deg8, 0, (size_t)8 * N_NODES * sizeof(int), stream);
    k_deg8<<<nEdgeBlocks, 256, 0, stream>>>(dst, deg8, rank);
    k_sumdeg<<<nScanBlocks, 256, 0, stream>>>(deg8, deg);
    k_scan1<<<nScanBlocks, 256, 0, stream>>>(deg, offs, bsum);
    k_scan2<<<1, 512, 0, stream>>>(bsum, nScanBlocks);
    k_offs8<<<nScanBlocks, 256, 0, stream>>>(offs, bsum, deg8, offs, offs8);
    k_place<<<nEdgeBlocks, 256, 0, stream>>>(src, dst, rank, offs8, csr);

    k_cast_x<<<nCastBlocks, 256, 0, stream>>>(x, xb);
    k_cast_w<<<4, 128, 0, stream>>>(Wl0, Wr0, Wl1, Wr1, Wt);

    // layer 0: h = relu(aggr@Wl0 + x@Wr0 + b0) -> xb (in place, bf16)
    k_aggr_b<<<nAggrBlocks, 256, 0, stream>>>(xb, offs, deg, csr, aggrb);
    k_gemm_mfma<1, 1><<<nGemmBlocks, 256, 0, stream>>>(aggrb, xb, Wt_l0, Wt_r0, b0, xb);

    // layer 1: out = aggr_h@Wl1 + h@Wr1 + b1 -> d_out (fp32)
    k_aggr_b<<<nAggrBlocks, 256, 0, stream>>>(xb, offs, deg, csr, aggrb);
    k_gemm_mfma<0, 0><<<nGemmBlocks, 256, 0, stream>>>(aggrb, xb, Wt_l1, Wt_r1, b1, out);
}

// Round 7
// 399.806 us; speedup vs baseline: 2.2051x; 1.0230x over previous
//
#include <hip/hip_runtime.h>
#include <hip/hip_bf16.h>

#define N_NODES 100000
#define N_EDGES 1600000
#define D 128

typedef __attribute__((ext_vector_type(8))) short short8;
typedef __attribute__((ext_vector_type(4))) float f32x4;

__device__ __forceinline__ float bf2f(unsigned short u) {
    union { unsigned int i; float f; } c; c.i = ((unsigned int)u) << 16; return c.f;
}
__device__ __forceinline__ unsigned short f2bf(float f) {
    union { float f; unsigned int i; } c; c.f = f;
    unsigned int u = c.i;
    return (unsigned short)((u + 0x7fffu + ((u >> 16) & 1u)) >> 16);   // RNE
}

// ---------------- CSR build, atomic-contention-minimized ----------------
// 8-way privatized degree histogram; atomic return value = per-copy rank,
// so placement needs no atomics at all.

__global__ __launch_bounds__(256) void k_deg8(const int* __restrict__ dst,
                                              int* __restrict__ deg8,
                                              int* __restrict__ rank) {
    int e = blockIdx.x * 256 + threadIdx.x;   // grid exact: 6250*256 == N_EDGES
    int c = blockIdx.x & 7;
    rank[e] = atomicAdd(&deg8[c * N_NODES + dst[e]], 1);
}

__global__ __launch_bounds__(256) void k_sumdeg(const int* __restrict__ deg8,
                                                int* __restrict__ deg) {
    int i = blockIdx.x * 256 + threadIdx.x;
    if (i < N_NODES) {
        int s = 0;
#pragma unroll
        for (int c = 0; c < 8; ++c) s += deg8[c * N_NODES + i];
        deg[i] = s;
    }
}

__global__ void k_scan1(const int* __restrict__ deg, int* __restrict__ offsP,
                        int* __restrict__ bsum) {
    __shared__ int s[256];
    int i = blockIdx.x * 256 + threadIdx.x;
    int v = (i < N_NODES) ? deg[i] : 0;
    s[threadIdx.x] = v;
    __syncthreads();
    for (int off = 1; off < 256; off <<= 1) {
        int t = (threadIdx.x >= off) ? s[threadIdx.x - off] : 0;
        __syncthreads();
        s[threadIdx.x] += t;
        __syncthreads();
    }
    if (i < N_NODES) offsP[i] = s[threadIdx.x] - v;
    if (threadIdx.x == 255) bsum[blockIdx.x] = s[255];
}

__global__ void k_scan2(int* __restrict__ bsum, int nb) {
    __shared__ int s[512];
    int t = threadIdx.x;
    int v = (t < nb) ? bsum[t] : 0;
    s[t] = v;
    __syncthreads();
    for (int off = 1; off < 512; off <<= 1) {
        int u = (t >= off) ? s[t - off] : 0;
        __syncthreads();
        s[t] += u;
        __syncthreads();
    }
    if (t < nb) bsum[t] = s[t] - v;
}

__global__ __launch_bounds__(256) void k_offs8(const int* __restrict__ offsP,
                                               const int* __restrict__ bsum,
                                               const int* __restrict__ deg8,
                                               int* __restrict__ offs,
                                               int* __restrict__ offs8) {
    int i = blockIdx.x * 256 + threadIdx.x;
    if (i < N_NODES) {
        int o = offsP[i] + bsum[blockIdx.x];
        offs[i] = o;
#pragma unroll
        for (int c = 0; c < 8; ++c) {
            offs8[c * N_NODES + i] = o;
            o += deg8[c * N_NODES + i];
        }
    }
}

__global__ __launch_bounds__(256) void k_place(const int* __restrict__ src,
                                               const int* __restrict__ dst,
                                               const int* __restrict__ rank,
                                               const int* __restrict__ offs8,
                                               int* __restrict__ csr) {
    int e = blockIdx.x * 256 + threadIdx.x;   // same geometry as k_deg8
    int c = blockIdx.x & 7;
    int d = dst[e];
    csr[offs8[c * N_NODES + d] + rank[e]] = src[e];
}

// ---------------- casts ----------------

__global__ __launch_bounds__(256) void k_cast_x(const float* __restrict__ x,
                                                unsigned short* __restrict__ xb) {
    int i = blockIdx.x * 256 + threadIdx.x;
    int base = i * 8;
    if (base < N_NODES * D) {
        float4 a = *(const float4*)&x[base];
        float4 b = *(const float4*)&x[base + 4];
        uint4 o;
        o.x = (unsigned)f2bf(a.x) | ((unsigned)f2bf(a.y) << 16);
        o.y = (unsigned)f2bf(a.z) | ((unsigned)f2bf(a.w) << 16);
        o.z = (unsigned)f2bf(b.x) | ((unsigned)f2bf(b.y) << 16);
        o.w = (unsigned)f2bf(b.z) | ((unsigned)f2bf(b.w) << 16);
        *(uint4*)&xb[base] = o;
    }
}

__global__ void k_cast_w(const float* __restrict__ W0, const float* __restrict__ W1,
                         const float* __restrict__ W2, const float* __restrict__ W3,
                         unsigned short* __restrict__ T) {
    const float* W = (blockIdx.x == 0) ? W0 : (blockIdx.x == 1) ? W1
                     : (blockIdx.x == 2) ? W2 : W3;
    unsigned short* Tm = T + blockIdx.x * D * D;
    int n = threadIdx.x;           // 128 threads
    for (int k = 0; k < D; ++k)
        Tm[n * D + k] = f2bf(W[k * D + n]);
}

// ---------------- mean aggregation v2 ----------------
// Wave split into two 32-lane halves; each half takes one edge of a pair.
// Lane loads uint2 (4 bf16 features) -> one wave load moves 512 B (2 edges).
// 8 edges in flight per unrolled iter. Final cross-half shfl_xor(32) reduce.

__global__ __launch_bounds__(256) void k_aggr_b(
    const unsigned short* __restrict__ xb, const int* __restrict__ offs,
    const int* __restrict__ deg, const int* __restrict__ csr,
    unsigned short* __restrict__ aggrb)
{
    int wave = threadIdx.x >> 6;
    int l = threadIdx.x & 63;
    int half = l >> 5;            // which edge of the pair
    int li = l & 31;              // feature quad: features [li*4, li*4+4)
    int node = blockIdx.x * 4 + wave;
    if (node >= N_NODES) return;
    int start = offs[node];
    int d = deg[node];
    float a0 = 0.f, a1 = 0.f, a2 = 0.f, a3 = 0.f;
    int e = 0;
    for (; e + 8 <= d; e += 8) {
        int j0 = csr[start + e + 0 + half];
        int j1 = csr[start + e + 2 + half];
        int j2 = csr[start + e + 4 + half];
        int j3 = csr[start + e + 6 + half];
        uint2 v0 = *(const uint2*)&xb[j0 * D + li * 4];
        uint2 v1 = *(const uint2*)&xb[j1 * D + li * 4];
        uint2 v2 = *(const uint2*)&xb[j2 * D + li * 4];
        uint2 v3 = *(const uint2*)&xb[j3 * D + li * 4];
        a0 += (bf2f(v0.x & 0xffff) + bf2f(v1.x & 0xffff)) + (bf2f(v2.x & 0xffff) + bf2f(v3.x & 0xffff));
        a1 += (bf2f(v0.x >> 16)    + bf2f(v1.x >> 16))    + (bf2f(v2.x >> 16)    + bf2f(v3.x >> 16));
        a2 += (bf2f(v0.y & 0xffff) + bf2f(v1.y & 0xffff)) + (bf2f(v2.y & 0xffff) + bf2f(v3.y & 0xffff));
        a3 += (bf2f(v0.y >> 16)    + bf2f(v1.y >> 16))    + (bf2f(v2.y >> 16)    + bf2f(v3.y >> 16));
    }
    for (; e + 2 <= d; e += 2) {
        int j = csr[start + e + half];
        uint2 v = *(const uint2*)&xb[j * D + li * 4];
        a0 += bf2f(v.x & 0xffff); a1 += bf2f(v.x >> 16);
        a2 += bf2f(v.y & 0xffff); a3 += bf2f(v.y >> 16);
    }
    if ((d & 1) && half == 0) {   // odd tail: half 0 only
        int j = csr[start + d - 1];
        uint2 v = *(const uint2*)&xb[j * D + li * 4];
        a0 += bf2f(v.x & 0xffff); a1 += bf2f(v.x >> 16);
        a2 += bf2f(v.y & 0xffff); a3 += bf2f(v.y >> 16);
    }
    a0 += __shfl_xor(a0, 32, 64);
    a1 += __shfl_xor(a1, 32, 64);
    a2 += __shfl_xor(a2, 32, 64);
    a3 += __shfl_xor(a3, 32, 64);
    if (half == 0) {
        float inv = 1.f / (float)(d > 0 ? d : 1);
        uint2 o;
        o.x = (unsigned)f2bf(a0 * inv) | ((unsigned)f2bf(a1 * inv) << 16);
        o.y = (unsigned)f2bf(a2 * inv) | ((unsigned)f2bf(a3 * inv) << 16);
        *(uint2*)&aggrb[node * D + li * 4] = o;
    }
}

// ---------------- MFMA GEMM: out = A@Wl + B@Wr + bias ----------------
// BM=128 rows/block, 4 waves x 32 rows (2 A-frags reused over 8 B-frags):
// per kt per wave 10 ds_read_b128 : 16 MFMA (was 9:8 -> LDS-read-bound).

template<int OUT_BF16, int RELU>
__global__ __launch_bounds__(256) void k_gemm_mfma(
    const unsigned short* __restrict__ Ab,   // aggr bf16 [N][D]
    const unsigned short* __restrict__ Bb,   // x/h  bf16 [N][D] (may alias out when OUT_BF16)
    const unsigned short* __restrict__ Wlt,  // [n][k] bf16
    const unsigned short* __restrict__ Wrt,  // [n][k] bf16
    const float* __restrict__ bias,
    void* __restrict__ outp)
{
    __shared__ unsigned short As[128][40];   // 128 rows x 32k (+8 pad)
    __shared__ unsigned short Ws[128][40];   // 128 n    x 32k (+8 pad)

    int tid = threadIdx.x;
    int w = tid >> 6;
    int l = tid & 63;
    int row0 = blockIdx.x * 128;

    f32x4 acc[2][8];
#pragma unroll
    for (int h = 0; h < 2; ++h)
#pragma unroll
        for (int nt = 0; nt < 8; ++nt) acc[h][nt] = (f32x4){0.f, 0.f, 0.f, 0.f};

    for (int kt = 0; kt < 8; ++kt) {
        const unsigned short* Asrc = (kt < 4) ? Ab : Bb;
        const unsigned short* Wsrc = (kt < 4) ? Wlt : Wrt;
        int k0 = (kt & 3) * 32;
        // stage A tile (128 x 32): 2 x uint4 per thread
#pragma unroll
        for (int rep = 0; rep < 2; ++rep) {
            int idx = tid + 256 * rep;
            int rr = idx >> 2, c4 = idx & 3;
            int arow = row0 + rr; if (arow > N_NODES - 1) arow = N_NODES - 1;
            *(uint4*)&As[rr][c4 * 8] = *(const uint4*)&Asrc[arow * D + k0 + c4 * 8];
        }
        // stage W tile (128 x 32)
#pragma unroll
        for (int rep = 0; rep < 2; ++rep) {
            int idx = tid + 256 * rep;
            int rr = idx >> 2, c4 = idx & 3;
            *(uint4*)&Ws[rr][c4 * 8] = *(const uint4*)&Wsrc[rr * D + k0 + c4 * 8];
        }
        __syncthreads();
        int kb = l >> 4, m16 = l & 15;
        short8 A0 = *(const short8*)&As[32 * w + m16][kb * 8];
        short8 A1 = *(const short8*)&As[32 * w + 16 + m16][kb * 8];
#pragma unroll
        for (int nt = 0; nt < 8; ++nt) {
            short8 b = *(const short8*)&Ws[nt * 16 + m16][kb * 8];
            acc[0][nt] = __builtin_amdgcn_mfma_f32_16x16x32_bf16(A0, b, acc[0][nt], 0, 0, 0);
            acc[1][nt] = __builtin_amdgcn_mfma_f32_16x16x32_bf16(A1, b, acc[1][nt], 0, 0, 0);
        }
        __syncthreads();
    }

    // epilogue: C[row=(l>>4)*4+i][col=l&15] per 16x16 tile (m89-verified)
    int cbase = l & 15;
#pragma unroll
    for (int h = 0; h < 2; ++h) {
        int rbase = row0 + 32 * w + 16 * h + ((l >> 4) << 2);
#pragma unroll
        for (int nt = 0; nt < 8; ++nt) {
            int col = nt * 16 + cbase;
            float bv = bias[col];
#pragma unroll
            for (int i = 0; i < 4; ++i) {
                int row = rbase + i;
                if (row < N_NODES) {
                    float v = acc[h][nt][i] + bv;
                    if (RELU) v = fmaxf(v, 0.f);
                    if (OUT_BF16) ((unsigned short*)outp)[row * D + col] = f2bf(v);
                    else          ((float*)outp)[row * D + col] = v;
                }
            }
        }
    }
}

// ---------------- launch ----------------

static inline size_t align_up(size_t v, size_t a) { return (v + a - 1) / a * a; }

extern "C" void kernel_launch(void* const* d_in, const int* in_sizes, int n_in,
                              void* d_out, int out_size, void* d_ws, size_t ws_size,
                              hipStream_t stream) {
    const float* x   = (const float*)d_in[0];
    const int*   ei  = (const int*)d_in[1];
    const int*   src = ei;
    const int*   dst = ei + N_EDGES;
    const float* Wl0 = (const float*)d_in[2];
    const float* b0  = (const float*)d_in[3];
    const float* Wr0 = (const float*)d_in[4];
    const float* Wl1 = (const float*)d_in[5];
    const float* b1  = (const float*)d_in[6];
    const float* Wr1 = (const float*)d_in[7];
    float* out = (float*)d_out;

    // workspace layout (~58.5 MB); deg8/rank/offs8 overlap aggrb (dead before
    // first k_aggr_b write).
    char* w = (char*)d_ws;
    int* deg    = (int*)w;                  w += align_up(N_NODES * 4, 256);
    int* offs   = (int*)w;                  w += align_up(N_NODES * 4, 256);
    int* bsum   = (int*)w;                  w += align_up(512 * 4, 256);
    int* csr    = (int*)w;                  w += align_up((size_t)N_EDGES * 4, 256);
    unsigned short* xb    = (unsigned short*)w;  w += align_up((size_t)N_NODES * D * 2, 256); // becomes h after layer 0
    unsigned short* Wt    = (unsigned short*)w;  w += align_up((size_t)4 * D * D * 2, 256);
    unsigned short* aggrb = (unsigned short*)w;  w += align_up((size_t)N_NODES * D * 2, 256);
    // transient region inside aggrb:
    int* deg8  = (int*)aggrb;                          // 3.2 MB
    int* rank  = deg8 + 8 * N_NODES;                   // 6.4 MB
    int* offs8 = rank + N_EDGES;                       // 3.2 MB  (total 12.8 < 25.6 MB)
    unsigned short* Wt_l0 = Wt + 0 * D * D;
    unsigned short* Wt_r0 = Wt + 1 * D * D;
    unsigned short* Wt_l1 = Wt + 2 * D * D;
    unsigned short* Wt_r1 = Wt + 3 * D * D;

    const int nScanBlocks = (N_NODES + 255) / 256;   // 391
    const int nEdgeBlocks = N_EDGES / 256;           // 6250 (exact)
    const int nCastBlocks = (N_NODES * D / 8 + 255) / 256;
    const int nAggrBlocks = N_NODES / 4;             // 25000
    const int nGemmBlocks = (N_NODES + 127) / 128;   // 782

    hipMemsetAsync(deg8, 0, (size_t)8 * N_NODES * sizeof(int), stream);
    k_deg8<<<nEdgeBlocks, 256, 0, stream>>>(dst, deg8, rank);
    k_sumdeg<<<nScanBlocks, 256, 0, stream>>>(deg8, deg);
    k_scan1<<<nScanBlocks, 256, 0, stream>>>(deg, offs, bsum);
    k_scan2<<<1, 512, 0, stream>>>(bsum, nScanBlocks);
    k_offs8<<<nScanBlocks, 256, 0, stream>>>(offs, bsum, deg8, offs, offs8);
    k_place<<<nEdgeBlocks, 256, 0, stream>>>(src, dst, rank, offs8, csr);

    k_cast_x<<<nCastBlocks, 256, 0, stream>>>(x, xb);
    k_cast_w<<<4, 128, 0, stream>>>(Wl0, Wr0, Wl1, Wr1, Wt);

    // layer 0: h = relu(aggr@Wl0 + x@Wr0 + b0) -> xb (in place, bf16)
    k_aggr_b<<<nAggrBlocks, 256, 0, stream>>>(xb, offs, deg, csr, aggrb);
    k_gemm_mfma<1, 1><<<nGemmBlocks, 256, 0, stream>>>(aggrb, xb, Wt_l0, Wt_r0, b0, xb);

    // layer 1: out = aggr_h@Wl1 + h@Wr1 + b1 -> d_out (fp32)
    k_aggr_b<<<nAggrBlocks, 256, 0, stream>>>(xb, offs, deg, csr, aggrb);
    k_gemm_mfma<0, 0><<<nGemmBlocks, 256, 0, stream>>>(aggrb, xb, Wt_l1, Wt_r1, b1, out);
}